// Round 7
// baseline (1833.863 us; speedup 1.0000x reference)
//
#include <hip/hip_runtime.h>

static constexpr int L_ = 2;      // layers
static constexpr int H_ = 1024;   // hidden
static constexpr int E_ = 1024;   // embedding
static constexpr int T_ = 64;     // steps
static constexpr int NB = 256;    // blocks (== CUs)
static constexpr int BT = 1024;   // threads per block (16 waves)

// ws layout (4-byte words). Data slots are write-once per step; flags are
// store-only (no RMW). Everything sentinel-filled 0xFF per call.
static constexpr int WS_XV = 0;                       // xv[T+1][H]
static constexpr int WS_H  = WS_XV + (T_ + 1) * H_;   // h[T][L][H]
static constexpr int WS_LG = WS_H + T_ * L_ * H_;     // lg[T][E]
static constexpr int WS_F0 = WS_LG + T_ * E_;         // h0 flags [T][NB]
static constexpr int WS_F1 = WS_F0 + T_ * NB;         // h1 flags [T][NB]
static constexpr int WS_F2 = WS_F1 + T_ * NB;         // lg flags [T][NB]
static constexpr int WS_F3 = WS_F2 + T_ * NB;         // xv flags [T+1][NB]
static constexpr size_t WS_BYTES = (size_t)(WS_F3 + (T_ + 1) * NB) * 4;

static constexpr unsigned SENT = 0xFFFFFFFFu;

__device__ __forceinline__ float sigm(float v) { return 1.0f / (1.0f + expf(-v)); }

__device__ __forceinline__ float cload(const float* p) {
  return __hip_atomic_load(p, __ATOMIC_RELAXED, __HIP_MEMORY_SCOPE_AGENT);
}
__device__ __forceinline__ void cstore(float* p, float v) {
  __hip_atomic_store(p, v, __ATOMIC_RELAXED, __HIP_MEMORY_SCOPE_AGENT);
}
__device__ __forceinline__ unsigned cloadu(const unsigned* p) {
  return __hip_atomic_load(p, __ATOMIC_RELAXED, __HIP_MEMORY_SCOPE_AGENT);
}
__device__ __forceinline__ void cstoreu(unsigned* p, unsigned v) {
  __hip_atomic_store(p, v, __ATOMIC_RELAXED, __HIP_MEMORY_SCOPE_AGENT);
}

// Watcher: one wave polls 256 per-block flags (lane i owns words 4i..4i+3).
__device__ __forceinline__ void wait256(const unsigned* f) {
  const int lane = threadIdx.x & 63;
  const unsigned* p = f + lane * 4;
  for (;;) {
    const unsigned a = cloadu(p + 0), b = cloadu(p + 1),
                   c = cloadu(p + 2), d = cloadu(p + 3);
    const bool ok = (a != SENT) & (b != SENT) & (c != SENT) & (d != SENT);
    if (__all(ok)) break;
  }
}

// Weight-stationary, store-only-handshake persistent controller.
// Wave w of block b permanently holds, in 64 registers (float4 wr[4][4]):
//   matrix-half (l = w>>3, q = (w>>1)&3, half = w&1 : 0=W_ih/x, 1=W_hh/h)
//   rows j = 4b+u (u=0..3), columns k = m*256 + lane*4 + {0..3}.
// Hop protocol: wave 0 cstores payload -> s_waitcnt vmcnt(0) -> lane 0
// cstores block flag. Consumer wave 15 polls the 256 flags, then the whole
// block loads the payload once. No atomics-RMW anywhere.
__global__ __launch_bounds__(BT, 4) void ctrl_kernel(
    const float* __restrict__ W_ih, const float* __restrict__ W_hh,
    const float* __restrict__ b_ih, const float* __restrict__ b_hh,
    const float* __restrict__ We,   const float* __restrict__ be,
    float* __restrict__ out, float* __restrict__ ws)
{
  const int tid  = threadIdx.x;
  const int b    = blockIdx.x;
  const int lane = tid & 63;
  const int w    = tid >> 6;       // wave 0..15
  const int wl   = w >> 3;         // layer this wave serves
  const int wq   = (w >> 1) & 3;   // gate index (i,f,g,o)
  const int wh   = w & 1;          // 0: W_ih/x-half, 1: W_hh/h-half

  float*    xv  = ws + WS_XV;
  float*    hh  = ws + WS_H;
  float*    lg  = ws + WS_LG;
  unsigned* wsu = (unsigned*)ws;
  unsigned* fh0 = wsu + WS_F0;
  unsigned* fh1 = wsu + WS_F1;
  unsigned* flg = wsu + WS_F2;
  unsigned* fxv = wsu + WS_F3;

  // feedback column ownership, XCD-swizzled
  const int cswz = ((b & 7) * 32 + (b >> 3)) * 4;

  __shared__ float  s_x[H_];            // staging: x / h0 / h1 / logits
  __shared__ float  s_h[H_];            // staging: h0(t-1)
  __shared__ float  s_h1[H_];           // staging: h1(t-1)
  __shared__ float  s_gd[2][4][2][4];   // gate partials [l][q][half][unit]
  __shared__ float  s_bias[2][4][4];    // combined biases [l][q][unit]
  __shared__ float  s_be[T_ * 4];       // be rows for this block, all steps
  __shared__ float  s_c[2][4];          // cell state [l][unit]
  __shared__ float  s_red[16];          // logits reduction scratch
  __shared__ float  s_redm[16];         // softmax max partials
  __shared__ float  s_reds[16];         // softmax sum partials
  __shared__ float4 s_part4[16];        // x_next per-wave partials

  // ---- prologue ----
  if (tid < 32) {
    const int l = tid >> 4, q = (tid >> 2) & 3, u = tid & 3;
    const int j = b * 4 + u;
    s_bias[l][q][u] = b_ih[(size_t)l * 4 * H_ + q * H_ + j]
                    + b_hh[(size_t)l * 4 * H_ + q * H_ + j];
  }
  if (tid < 8) s_c[tid >> 2][tid & 3] = 0.0f;
  if (tid < T_ * 4)   // be[t][b*4+u] -> LDS (keeps be off the critical path)
    s_be[tid] = be[(size_t)(tid >> 2) * E_ + b * 4 + (tid & 3)];

  float4 wr[4][4];
  {
    const float* Wbase = (wh == 0) ? W_ih : W_hh;
    #pragma unroll
    for (int u = 0; u < 4; ++u) {
      const size_t row = (size_t)wl * 4 * H_ * H_
                       + ((size_t)wq * H_ + (size_t)(b * 4 + u)) * (size_t)H_;
      #pragma unroll
      for (int m = 0; m < 4; ++m)
        wr[u][m] = *(const float4*)&Wbase[row + (size_t)m * 256 + lane * 4];
    }
  }
  #pragma unroll
  for (int u = 0; u < 4; ++u)
    #pragma unroll
    for (int m = 0; m < 4; ++m)
      asm volatile("" : "+v"(wr[u][m].x), "+v"(wr[u][m].y),
                        "+v"(wr[u][m].z), "+v"(wr[u][m].w));

  for (int t = 0; t < T_; ++t) {
    const float* We_t = We + (size_t)t * E_ * H_;

    // ===== phase A: stage x(t), h0(t-1), h1(t-1); l0 gates + l1 h-half =====
    if (t == 0) {
      s_x[tid] = 0.0f; s_h[tid] = 0.0f; s_h1[tid] = 0.0f;
    } else {
      if (w == 15) wait256(fxv + (size_t)t * NB);  // h flags observed in t-1
      __syncthreads();
      s_x[tid]  = cload(&xv[(size_t)t * H_ + tid]);
      s_h[tid]  = cload(&hh[((size_t)(t - 1) * L_ + 0) * H_ + tid]);
      s_h1[tid] = cload(&hh[((size_t)(t - 1) * L_ + 1) * H_ + tid]);
    }
    __syncthreads();
    if (wl == 0 || wh == 1) {
      const float4* vin = (wl == 0) ? ((wh == 0) ? (const float4*)s_x : (const float4*)s_h)
                                    : (const float4*)s_h1;
      float a0 = 0.f, a1 = 0.f, a2 = 0.f, a3 = 0.f;
      #pragma unroll
      for (int m = 0; m < 4; ++m) {
        const float4 x4 = vin[m * 64 + lane];
        a0 += wr[0][m].x * x4.x + wr[0][m].y * x4.y + wr[0][m].z * x4.z + wr[0][m].w * x4.w;
        a1 += wr[1][m].x * x4.x + wr[1][m].y * x4.y + wr[1][m].z * x4.z + wr[1][m].w * x4.w;
        a2 += wr[2][m].x * x4.x + wr[2][m].y * x4.y + wr[2][m].z * x4.z + wr[2][m].w * x4.w;
        a3 += wr[3][m].x * x4.x + wr[3][m].y * x4.y + wr[3][m].z * x4.z + wr[3][m].w * x4.w;
      }
      #pragma unroll
      for (int off = 32; off; off >>= 1) {
        a0 += __shfl_down(a0, off, 64);
        a1 += __shfl_down(a1, off, 64);
        a2 += __shfl_down(a2, off, 64);
        a3 += __shfl_down(a3, off, 64);
      }
      if (lane == 0) {
        s_gd[wl][wq][wh][0] = a0; s_gd[wl][wq][wh][1] = a1;
        s_gd[wl][wq][wh][2] = a2; s_gd[wl][wq][wh][3] = a3;
      }
    }
    __syncthreads();
    if (tid < 4) {   // l0 epilogue -> publish h[t][0]
      const int u = tid;
      const float g0 = s_gd[0][0][0][u] + s_gd[0][0][1][u] + s_bias[0][0][u];
      const float g1 = s_gd[0][1][0][u] + s_gd[0][1][1][u] + s_bias[0][1][u];
      const float g2 = s_gd[0][2][0][u] + s_gd[0][2][1][u] + s_bias[0][2][u];
      const float g3 = s_gd[0][3][0][u] + s_gd[0][3][1][u] + s_bias[0][3][u];
      const float cn = sigm(g1) * s_c[0][u] + sigm(g0) * tanhf(g2);
      s_c[0][u] = cn;
      cstore(&hh[((size_t)t * L_ + 0) * H_ + b * 4 + u], sigm(g3) * tanhf(cn));
    }
    if (w == 0) {
      asm volatile("s_waitcnt vmcnt(0)" ::: "memory");
      if (lane == 0) cstoreu(fh0 + (size_t)t * NB + b, 1u);
    }

    // prefetch this step's We operands AFTER phase-A publish so the
    // vmcnt(0) above never waits on the 4 MB stream; used in phases C/D
    const float4 wlog = *(const float4*)&We_t[((size_t)(b * 4 + (tid >> 8))) * H_ + (tid & 255) * 4];
    const float4 wfb  = *(const float4*)&We_t[(size_t)tid * H_ + cswz];

    // ===== phase B: stage h[t][0]; l1 x-half; publish h[t][1] =====
    if (w == 15) wait256(fh0 + (size_t)t * NB);
    __syncthreads();
    s_x[tid] = cload(&hh[((size_t)t * L_ + 0) * H_ + tid]);
    __syncthreads();
    if (wl == 1 && wh == 0) {
      const float4* vin = (const float4*)s_x;
      float a0 = 0.f, a1 = 0.f, a2 = 0.f, a3 = 0.f;
      #pragma unroll
      for (int m = 0; m < 4; ++m) {
        const float4 x4 = vin[m * 64 + lane];
        a0 += wr[0][m].x * x4.x + wr[0][m].y * x4.y + wr[0][m].z * x4.z + wr[0][m].w * x4.w;
        a1 += wr[1][m].x * x4.x + wr[1][m].y * x4.y + wr[1][m].z * x4.z + wr[1][m].w * x4.w;
        a2 += wr[2][m].x * x4.x + wr[2][m].y * x4.y + wr[2][m].z * x4.z + wr[2][m].w * x4.w;
        a3 += wr[3][m].x * x4.x + wr[3][m].y * x4.y + wr[3][m].z * x4.z + wr[3][m].w * x4.w;
      }
      #pragma unroll
      for (int off = 32; off; off >>= 1) {
        a0 += __shfl_down(a0, off, 64);
        a1 += __shfl_down(a1, off, 64);
        a2 += __shfl_down(a2, off, 64);
        a3 += __shfl_down(a3, off, 64);
      }
      if (lane == 0) {
        s_gd[1][wq][0][0] = a0; s_gd[1][wq][0][1] = a1;
        s_gd[1][wq][0][2] = a2; s_gd[1][wq][0][3] = a3;
      }
    }
    __syncthreads();
    if (tid < 4) {   // l1 epilogue -> publish h[t][1]
      const int u = tid;
      const float g0 = s_gd[1][0][0][u] + s_gd[1][0][1][u] + s_bias[1][0][u];
      const float g1 = s_gd[1][1][0][u] + s_gd[1][1][1][u] + s_bias[1][1][u];
      const float g2 = s_gd[1][2][0][u] + s_gd[1][2][1][u] + s_bias[1][2][u];
      const float g3 = s_gd[1][3][0][u] + s_gd[1][3][1][u] + s_bias[1][3][u];
      const float cn = sigm(g1) * s_c[1][u] + sigm(g0) * tanhf(g2);
      s_c[1][u] = cn;
      cstore(&hh[((size_t)t * L_ + 1) * H_ + b * 4 + u], sigm(g3) * tanhf(cn));
    }
    if (w == 0) {
      asm volatile("s_waitcnt vmcnt(0)" ::: "memory");
      if (lane == 0) cstoreu(fh1 + (size_t)t * NB + b, 1u);
    }

    // ===== phase C: logits rows 4b..4b+3 =====
    if (w == 15) wait256(fh1 + (size_t)t * NB);
    __syncthreads();
    s_x[tid] = cload(&hh[((size_t)t * L_ + 1) * H_ + tid]);
    __syncthreads();
    {
      const float4 h4 = ((const float4*)s_x)[tid & 255];
      float a = wlog.x * h4.x + wlog.y * h4.y + wlog.z * h4.z + wlog.w * h4.w;
      #pragma unroll
      for (int off = 32; off; off >>= 1) a += __shfl_down(a, off, 64);
      if (lane == 0) s_red[w] = a;
    }
    __syncthreads();
    if (tid < 4) {   // wave 0 sums row partials -> publish logits
      const float v = s_red[tid * 4] + s_red[tid * 4 + 1] + s_red[tid * 4 + 2]
                    + s_red[tid * 4 + 3] + s_be[t * 4 + tid];
      cstore(&lg[(size_t)t * E_ + b * 4 + tid], v);
    }
    if (w == 0) {
      asm volatile("s_waitcnt vmcnt(0)" ::: "memory");
      if (lane == 0) cstoreu(flg + (size_t)t * NB + b, 1u);
    }

    // ===== phase D: softmax + decisions + x_next cols cswz..cswz+3 =====
    if (w == 15) wait256(flg + (size_t)t * NB);
    __syncthreads();
    s_x[tid] = cload(&lg[(size_t)t * E_ + tid]);
    __syncthreads();
    {
      const float v = s_x[tid];
      float mm = v;
      #pragma unroll
      for (int off = 32; off; off >>= 1) mm = fmaxf(mm, __shfl_down(mm, off, 64));
      if (lane == 0) s_redm[w] = mm;
      __syncthreads();
      mm = s_redm[0];
      #pragma unroll
      for (int k = 1; k < 16; ++k) mm = fmaxf(mm, s_redm[k]);
      const float ev = expf(v - mm);        // e = tid
      float sv = ev;
      #pragma unroll
      for (int off = 32; off; off >>= 1) sv += __shfl_down(sv, off, 64);
      if (lane == 0) s_reds[w] = sv;
      __syncthreads();
      float ssum = 0.f;
      #pragma unroll
      for (int k = 0; k < 16; ++k) ssum += s_reds[k];
      const float inv = 1.0f / ssum;
      const float d = ev * inv;             // decision[e = tid], all blocks agree

      if ((tid >> 2) == b) out[(size_t)t * E_ + tid] = d;  // block b writes its 4

      float4 acc = make_float4(d * wfb.x, d * wfb.y, d * wfb.z, d * wfb.w);
      #pragma unroll
      for (int off = 32; off; off >>= 1) {
        acc.x += __shfl_down(acc.x, off, 64);
        acc.y += __shfl_down(acc.y, off, 64);
        acc.z += __shfl_down(acc.z, off, 64);
        acc.w += __shfl_down(acc.w, off, 64);
      }
      if (lane == 0) s_part4[w] = acc;
      __syncthreads();
      if (tid < 4) {
        float s = 0.f;
        #pragma unroll
        for (int k = 0; k < 16; ++k)
          s += ((const float*)&s_part4[k])[tid];
        cstore(&xv[(size_t)(t + 1) * H_ + cswz + tid], s);  // x for step t+1
      }
      if (w == 0) {
        asm volatile("s_waitcnt vmcnt(0)" ::: "memory");
        if (lane == 0) cstoreu(fxv + (size_t)(t + 1) * NB + b, 1u);
      }
    }
  }
}

extern "C" void kernel_launch(void* const* d_in, const int* in_sizes, int n_in,
                              void* d_out, int out_size, void* d_ws, size_t ws_size,
                              hipStream_t stream) {
  const float* W_ih = (const float*)d_in[0];
  const float* W_hh = (const float*)d_in[1];
  const float* b_ih = (const float*)d_in[2];
  const float* b_hh = (const float*)d_in[3];
  const float* We   = (const float*)d_in[4];
  const float* be   = (const float*)d_in[5];
  float* out = (float*)d_out;
  float* ws  = (float*)d_ws;

  // sentinel-fill all data slots + flags (graph-capturable, every call)
  (void)hipMemsetAsync(ws, 0xFF, WS_BYTES, stream);

  void* args[] = {(void*)&W_ih, (void*)&W_hh, (void*)&b_ih, (void*)&b_hh,
                  (void*)&We,   (void*)&be,   (void*)&out,  (void*)&ws};
  (void)hipLaunchCooperativeKernel((const void*)ctrl_kernel, dim3(NB), dim3(BT),
                                   args, 0, stream);
}

// Round 8
// 990.096 us; speedup vs baseline: 1.8522x; 1.8522x over previous
//
#include <hip/hip_runtime.h>

static constexpr int L_ = 2;      // layers
static constexpr int H_ = 1024;   // hidden
static constexpr int E_ = 1024;   // embedding
static constexpr int T_ = 64;     // steps
static constexpr int NB = 256;    // blocks (== CUs)
static constexpr int BT = 1024;   // threads per block (16 waves)

// ws layout (floats) — pure dataflow, write-once per-step slots, NO flags.
// Sentinel-filled 0xFF per call; every produced value is finite, so
// "bits != 0xFFFFFFFF" == "data ready".
static constexpr int WS_XV = 0;                       // xv[T+1][H]
static constexpr int WS_H  = WS_XV + (T_ + 1) * H_;   // h[T][L][H]
static constexpr int WS_LG = WS_H + T_ * L_ * H_;     // lg[T][E]
static constexpr size_t WS_BYTES = (size_t)(WS_LG + T_ * E_) * 4;

static constexpr unsigned SENT = 0xFFFFFFFFu;

__device__ __forceinline__ float sigm(float v) { return 1.0f / (1.0f + expf(-v)); }

__device__ __forceinline__ unsigned cloadu(const float* p) {
  return __hip_atomic_load((const unsigned*)p, __ATOMIC_RELAXED, __HIP_MEMORY_SCOPE_AGENT);
}
__device__ __forceinline__ void cstore(float* p, float v) {
  __hip_atomic_store(p, v, __ATOMIC_RELAXED, __HIP_MEMORY_SCOPE_AGENT);
}
__device__ __forceinline__ float poll1(const float* p) {
  unsigned v = cloadu(p);
  while (v == SENT) { __builtin_amdgcn_s_sleep(1); v = cloadu(p); }
  return __uint_as_float(v);
}

// Weight-stationary, barrier-free, flag-free persistent controller.
// Wave w of block b permanently holds, in 64 registers (float4 wr[4][4]):
//   role (l = w>>3, q = (w>>1)&3, half = w&1 : 0=W_ih, 1=W_hh),
//   rows j = 4b+u (u=0..3), columns k = m*256 + lane*4 + {0..3}.
// Phase schedule (critical path has exactly 4 chip-wide hops/step):
//   A: poll xv(t)      -> l0 x-half dots            -> publish h0(t)
//   B: poll h0(t)      -> l1 x-half dots [critical]
//                         + l0 h-half dots for t+1  -> publish h1(t)
//   C: poll h1(t)      -> logits rows [all waves]
//                         + l1 h-half dots for t+1  -> publish lg(t)
//   D: poll lg(t)      -> softmax + out + feedback  -> publish xv(t+1)
//      then issue We(t+1) prefetch (after last barrier, so the loads can
//      only delay the next xv-poll consume, which is ~1us later anyway).
__global__ __launch_bounds__(BT, 4) void ctrl_kernel(
    const float* __restrict__ W_ih, const float* __restrict__ W_hh,
    const float* __restrict__ b_ih, const float* __restrict__ b_hh,
    const float* __restrict__ We,   const float* __restrict__ be,
    float* __restrict__ out, float* __restrict__ ws)
{
  const int tid  = threadIdx.x;
  const int b    = blockIdx.x;
  const int lane = tid & 63;
  const int w    = tid >> 6;       // wave 0..15
  const int wl   = w >> 3;         // layer of this wave's weights
  const int wq   = (w >> 1) & 3;   // gate index (i,f,g,o)
  const int wh   = w & 1;          // 0: W_ih half, 1: W_hh half

  float* xv = ws + WS_XV;
  float* hh = ws + WS_H;
  float* lg = ws + WS_LG;

  // feedback column ownership, XCD-swizzled
  const int cswz = ((b & 7) * 32 + (b >> 3)) * 4;

  __shared__ float  s_x[H_];            // staging: x / h0 / h1 / logits
  __shared__ float  s_gd[2][4][2][4];   // gate partials [l][q][half][unit]
  __shared__ float  s_bias[2][4][4];    // combined biases [l][q][unit]
  __shared__ float  s_be[T_ * 4];       // be rows for this block, all steps
  __shared__ float  s_c[2][4];          // cell state [l][unit]
  __shared__ float  s_red[16];          // logits reduction scratch
  __shared__ float  s_redm[16];         // softmax max partials
  __shared__ float  s_reds[16];         // softmax sum partials
  __shared__ float4 s_part4[16];        // x_next per-wave partials

  // ---- prologue ----
  if (tid < 32) {
    const int l = tid >> 4, q = (tid >> 2) & 3, u = tid & 3;
    const int j = b * 4 + u;
    s_bias[l][q][u] = b_ih[(size_t)l * 4 * H_ + q * H_ + j]
                    + b_hh[(size_t)l * 4 * H_ + q * H_ + j];
  }
  if (tid < 8) s_c[tid >> 2][tid & 3] = 0.0f;
  if (tid < 64) ((float*)s_gd)[tid] = 0.0f;   // h-half partials start at 0
  if (tid < T_ * 4)
    s_be[tid] = be[(size_t)(tid >> 2) * E_ + b * 4 + (tid & 3)];

  float4 wr[4][4];
  {
    const float* Wbase = (wh == 0) ? W_ih : W_hh;
    #pragma unroll
    for (int u = 0; u < 4; ++u) {
      const size_t row = (size_t)wl * 4 * H_ * H_
                       + ((size_t)wq * H_ + (size_t)(b * 4 + u)) * (size_t)H_;
      #pragma unroll
      for (int m = 0; m < 4; ++m)
        wr[u][m] = *(const float4*)&Wbase[row + (size_t)m * 256 + lane * 4];
    }
  }
  #pragma unroll
  for (int u = 0; u < 4; ++u)
    #pragma unroll
    for (int m = 0; m < 4; ++m)
      asm volatile("" : "+v"(wr[u][m].x), "+v"(wr[u][m].y),
                        "+v"(wr[u][m].z), "+v"(wr[u][m].w));

  // dot of this wave's held weight strip against vin, into s_gd[dl][dq][dh]
  auto dot_to = [&](const float4* vin, int dl, int dq, int dh) {
    float a0 = 0.f, a1 = 0.f, a2 = 0.f, a3 = 0.f;
    #pragma unroll
    for (int m = 0; m < 4; ++m) {
      const float4 x4 = vin[m * 64 + lane];
      a0 += wr[0][m].x * x4.x + wr[0][m].y * x4.y + wr[0][m].z * x4.z + wr[0][m].w * x4.w;
      a1 += wr[1][m].x * x4.x + wr[1][m].y * x4.y + wr[1][m].z * x4.z + wr[1][m].w * x4.w;
      a2 += wr[2][m].x * x4.x + wr[2][m].y * x4.y + wr[2][m].z * x4.z + wr[2][m].w * x4.w;
      a3 += wr[3][m].x * x4.x + wr[3][m].y * x4.y + wr[3][m].z * x4.z + wr[3][m].w * x4.w;
    }
    #pragma unroll
    for (int off = 32; off; off >>= 1) {
      a0 += __shfl_down(a0, off, 64);
      a1 += __shfl_down(a1, off, 64);
      a2 += __shfl_down(a2, off, 64);
      a3 += __shfl_down(a3, off, 64);
    }
    if (lane == 0) {
      s_gd[dl][dq][dh][0] = a0; s_gd[dl][dq][dh][1] = a1;
      s_gd[dl][dq][dh][2] = a2; s_gd[dl][dq][dh][3] = a3;
    }
  };

  // prefetch step-0 We operands (drained harmlessly at phase-A barrier)
  float4 wlog = *(const float4*)&We[((size_t)(b * 4 + (tid >> 8))) * H_ + (tid & 255) * 4];
  float4 wfb  = *(const float4*)&We[(size_t)tid * H_ + cswz];

  for (int t = 0; t < T_; ++t) {
    // ===== phase A: poll xv(t); l0 x-half; publish h0(t) =====
    if (t == 0) s_x[tid] = 0.0f;
    else        s_x[tid] = poll1(&xv[(size_t)t * H_ + tid]);
    __syncthreads();
    if (wl == 0 && wh == 0) dot_to((const float4*)s_x, 0, wq, 0);
    __syncthreads();
    if (tid < 4) {   // l0 epilogue (h-half partials came from phase B of t-1)
      const int u = tid;
      const float g0 = s_gd[0][0][0][u] + s_gd[0][0][1][u] + s_bias[0][0][u];
      const float g1 = s_gd[0][1][0][u] + s_gd[0][1][1][u] + s_bias[0][1][u];
      const float g2 = s_gd[0][2][0][u] + s_gd[0][2][1][u] + s_bias[0][2][u];
      const float g3 = s_gd[0][3][0][u] + s_gd[0][3][1][u] + s_bias[0][3][u];
      const float cn = sigm(g1) * s_c[0][u] + sigm(g0) * tanhf(g2);
      s_c[0][u] = cn;
      cstore(&hh[((size_t)t * L_ + 0) * H_ + b * 4 + u], sigm(g3) * tanhf(cn));
    }

    // ===== phase B: poll h0(t); l1 x-half (critical) + l0 h-half (t+1) =====
    s_x[tid] = poll1(&hh[((size_t)t * L_ + 0) * H_ + tid]);
    __syncthreads();
    if (wl == 1 && wh == 0) dot_to((const float4*)s_x, 1, wq, 0);  // critical
    if (wl == 0 && wh == 1) dot_to((const float4*)s_x, 0, wq, 1);  // for t+1
    __syncthreads();
    if (tid < 4) {   // l1 epilogue (h-half partials came from phase C of t-1)
      const int u = tid;
      const float g0 = s_gd[1][0][0][u] + s_gd[1][0][1][u] + s_bias[1][0][u];
      const float g1 = s_gd[1][1][0][u] + s_gd[1][1][1][u] + s_bias[1][1][u];
      const float g2 = s_gd[1][2][0][u] + s_gd[1][2][1][u] + s_bias[1][2][u];
      const float g3 = s_gd[1][3][0][u] + s_gd[1][3][1][u] + s_bias[1][3][u];
      const float cn = sigm(g1) * s_c[1][u] + sigm(g0) * tanhf(g2);
      s_c[1][u] = cn;
      cstore(&hh[((size_t)t * L_ + 1) * H_ + b * 4 + u], sigm(g3) * tanhf(cn));
    }

    // ===== phase C: poll h1(t); logits rows + l1 h-half (t+1) =====
    s_x[tid] = poll1(&hh[((size_t)t * L_ + 1) * H_ + tid]);
    __syncthreads();
    {
      const float4 h4 = ((const float4*)s_x)[tid & 255];
      float a = wlog.x * h4.x + wlog.y * h4.y + wlog.z * h4.z + wlog.w * h4.w;
      #pragma unroll
      for (int off = 32; off; off >>= 1) a += __shfl_down(a, off, 64);
      if (lane == 0) s_red[w] = a;
    }
    if (wl == 1 && wh == 1) dot_to((const float4*)s_x, 1, wq, 1);  // for t+1
    __syncthreads();
    if (tid < 4) {   // sum the 4 wave-partials per row -> publish logits
      const float v = s_red[tid * 4] + s_red[tid * 4 + 1] + s_red[tid * 4 + 2]
                    + s_red[tid * 4 + 3] + s_be[t * 4 + tid];
      cstore(&lg[(size_t)t * E_ + b * 4 + tid], v);
    }

    // ===== phase D: poll lg(t); softmax + out + feedback; publish xv(t+1) =====
    s_x[tid] = poll1(&lg[(size_t)t * E_ + tid]);
    __syncthreads();
    {
      const float v = s_x[tid];
      float mm = v;
      #pragma unroll
      for (int off = 32; off; off >>= 1) mm = fmaxf(mm, __shfl_down(mm, off, 64));
      if (lane == 0) s_redm[w] = mm;
      __syncthreads();
      mm = s_redm[0];
      #pragma unroll
      for (int k = 1; k < 16; ++k) mm = fmaxf(mm, s_redm[k]);
      const float ev = expf(v - mm);        // e = tid
      float sv = ev;
      #pragma unroll
      for (int off = 32; off; off >>= 1) sv += __shfl_down(sv, off, 64);
      if (lane == 0) s_reds[w] = sv;
      __syncthreads();
      float ssum = 0.f;
      #pragma unroll
      for (int k = 0; k < 16; ++k) ssum += s_reds[k];
      const float inv = 1.0f / ssum;
      const float d = ev * inv;             // decision[e = tid], all blocks agree

      if ((tid >> 2) == b) out[(size_t)t * E_ + tid] = d;  // block b writes its 4

      float4 acc = make_float4(d * wfb.x, d * wfb.y, d * wfb.z, d * wfb.w);
      #pragma unroll
      for (int off = 32; off; off >>= 1) {
        acc.x += __shfl_down(acc.x, off, 64);
        acc.y += __shfl_down(acc.y, off, 64);
        acc.z += __shfl_down(acc.z, off, 64);
        acc.w += __shfl_down(acc.w, off, 64);
      }
      if (lane == 0) s_part4[w] = acc;
      __syncthreads();
      if (tid < 4) {
        float s = 0.f;
        #pragma unroll
        for (int k = 0; k < 16; ++k)
          s += ((const float*)&s_part4[k])[tid];
        cstore(&xv[(size_t)(t + 1) * H_ + cswz + tid], s);  // x for step t+1
      }
    }

    // issue next step's We prefetch AFTER the last barrier of the step:
    // these loads can only delay the next xv-poll consume (~1us later),
    // never a mid-step hop (in-order vmcnt, the R6/R7 failure mode).
    if (t + 1 < T_) {
      const float* Wn = We + (size_t)(t + 1) * E_ * H_;
      wlog = *(const float4*)&Wn[((size_t)(b * 4 + (tid >> 8))) * H_ + (tid & 255) * 4];
      wfb  = *(const float4*)&Wn[(size_t)tid * H_ + cswz];
    }
  }
}

extern "C" void kernel_launch(void* const* d_in, const int* in_sizes, int n_in,
                              void* d_out, int out_size, void* d_ws, size_t ws_size,
                              hipStream_t stream) {
  const float* W_ih = (const float*)d_in[0];
  const float* W_hh = (const float*)d_in[1];
  const float* b_ih = (const float*)d_in[2];
  const float* b_hh = (const float*)d_in[3];
  const float* We   = (const float*)d_in[4];
  const float* be   = (const float*)d_in[5];
  float* out = (float*)d_out;
  float* ws  = (float*)d_ws;

  // sentinel-fill all dataflow slots (graph-capturable, replayed every call)
  (void)hipMemsetAsync(ws, 0xFF, WS_BYTES, stream);

  void* args[] = {(void*)&W_ih, (void*)&W_hh, (void*)&b_ih, (void*)&b_hh,
                  (void*)&We,   (void*)&be,   (void*)&out,  (void*)&ws};
  (void)hipLaunchCooperativeKernel((const void*)ctrl_kernel, dim3(NB), dim3(BT),
                                   args, 0, stream);
}